// Round 1
// baseline (255.702 us; speedup 1.0000x reference)
//
#include <hip/hip_runtime.h>

// Q = L @ L^T for 3x3 lower-triangular L packed as 6 floats per item:
// packed order (row,col) = (0,0),(1,0),(1,1),(2,0),(2,1),(2,2) -> a,b,c,d,e,f
// Q row-major 3x3:
//   [a*a,      a*b,        a*d      ]
//   [a*b,      b*b+c*c,    b*d+c*e  ]
//   [a*d,      b*d+c*e,    d*d+e*e+f*f]
//
// Memory-bound: 24 B in + 36 B out per item. One thread processes 4 items so
// loads are 6x float4 and stores are 9x float4 (16 B/lane coalescing sweet
// spot; all cache-line bytes consumed).

__global__ __launch_bounds__(256) void chol_to_cov_kernel(
    const float* __restrict__ in, float* __restrict__ out, int n_items) {
  const int t = blockIdx.x * blockDim.x + threadIdx.x;
  const long long base = (long long)t * 4;
  if (base >= n_items) return;

  if (base + 4 <= n_items) {
    // vector path: 4 items per thread
    const float4* in4 = (const float4*)(in) + (long long)t * 6;
    float4* out4 = (float4*)(out) + (long long)t * 9;

    float s[24];
    float4 v;
#pragma unroll
    for (int k = 0; k < 6; k++) {
      v = in4[k];
      s[k * 4 + 0] = v.x;
      s[k * 4 + 1] = v.y;
      s[k * 4 + 2] = v.z;
      s[k * 4 + 3] = v.w;
    }

    float q[36];
#pragma unroll
    for (int i = 0; i < 4; i++) {
      const float a = s[i * 6 + 0];
      const float b = s[i * 6 + 1];
      const float c = s[i * 6 + 2];
      const float d = s[i * 6 + 3];
      const float e = s[i * 6 + 4];
      const float f = s[i * 6 + 5];
      const float q00 = a * a;
      const float q01 = a * b;
      const float q02 = a * d;
      const float q11 = b * b + c * c;
      const float q12 = b * d + c * e;
      const float q22 = d * d + e * e + f * f;
      q[i * 9 + 0] = q00;
      q[i * 9 + 1] = q01;
      q[i * 9 + 2] = q02;
      q[i * 9 + 3] = q01;
      q[i * 9 + 4] = q11;
      q[i * 9 + 5] = q12;
      q[i * 9 + 6] = q02;
      q[i * 9 + 7] = q12;
      q[i * 9 + 8] = q22;
    }

#pragma unroll
    for (int k = 0; k < 9; k++) {
      out4[k] = make_float4(q[k * 4 + 0], q[k * 4 + 1], q[k * 4 + 2],
                            q[k * 4 + 3]);
    }
  } else {
    // scalar tail (unused at 4096*1024 items, kept for safety)
    for (long long it = base; it < n_items; it++) {
      const float a = in[it * 6 + 0];
      const float b = in[it * 6 + 1];
      const float c = in[it * 6 + 2];
      const float d = in[it * 6 + 3];
      const float e = in[it * 6 + 4];
      const float f = in[it * 6 + 5];
      float* o = out + it * 9;
      o[0] = a * a;
      o[1] = a * b;
      o[2] = a * d;
      o[3] = a * b;
      o[4] = b * b + c * c;
      o[5] = b * d + c * e;
      o[6] = a * d;
      o[7] = b * d + c * e;
      o[8] = d * d + e * e + f * f;
    }
  }
}

extern "C" void kernel_launch(void* const* d_in, const int* in_sizes, int n_in,
                              void* d_out, int out_size, void* d_ws,
                              size_t ws_size, hipStream_t stream) {
  const float* in = (const float*)d_in[0];
  float* out = (float*)d_out;
  const int n_items = in_sizes[0] / 6;  // 4096*1024 = 4,194,304
  const int n_threads = (n_items + 3) / 4;
  const int block = 256;
  const int grid = (n_threads + block - 1) / block;
  chol_to_cov_kernel<<<grid, block, 0, stream>>>(in, out, n_items);
}

// Round 2
// 223.633 us; speedup vs baseline: 1.1434x; 1.1434x over previous
//
#include <hip/hip_runtime.h>

// Q = L @ L^T for 3x3 lower-triangular L packed as 6 floats per item:
// packed order (row,col) = (0,0),(1,0),(1,1),(2,0),(2,1),(2,2) -> a,b,c,d,e,f
// Q row-major 3x3:
//   [a*a,   a*b,     a*d      ]
//   [a*b,   b*b+c*c, b*d+c*e  ]
//   [a*d,   b*d+c*e, d*d+e*e+f*f]
//
// R1 lesson: per-INSTRUCTION lane contiguity is what matters for VMEM, not
// eventual line coverage. 96/144-B lane strides serialized address processing
// (~1.0 TB/s). This version stages through LDS so every global load/store is
// lane-contiguous float4 (16 B/lane, 8 lines/instruction).

#define THREADS 256
#define ITEMS_PER_BLOCK 1024  // 6 KF in (24 KB), 9 KF out (36 KB) -> 60 KB LDS

__global__ __launch_bounds__(THREADS) void chol_to_cov_kernel(
    const float* __restrict__ in, float* __restrict__ out, long long n_items) {
  __shared__ float s_in[ITEMS_PER_BLOCK * 6];   // 24 KB
  __shared__ float s_out[ITEMS_PER_BLOCK * 9];  // 36 KB

  const int tid = threadIdx.x;
  const long long block_base = (long long)blockIdx.x * ITEMS_PER_BLOCK;

  if (block_base + ITEMS_PER_BLOCK <= n_items) {
    // ---- fast path: fully coalesced ----
    // global -> LDS: 1536 float4, 6 per thread, lane stride 16 B
    const float4* __restrict__ in4 = (const float4*)(in + block_base * 6);
    float4* s_in4 = (float4*)s_in;
#pragma unroll
    for (int k = 0; k < 6; k++) {
      s_in4[tid + k * THREADS] = in4[tid + k * THREADS];
    }
    __syncthreads();

    // compute: item = tid + k*256. LDS read stride 6 (4-way bank alias, ~ok),
    // LDS write stride 9 (gcd(9,32)=1 -> conflict-free).
#pragma unroll
    for (int k = 0; k < 4; k++) {
      const int item = tid + k * THREADS;
      const float* s = s_in + item * 6;
      const float a = s[0], b = s[1], c = s[2], d = s[3], e = s[4], f = s[5];
      const float q00 = a * a;
      const float q01 = a * b;
      const float q02 = a * d;
      const float q11 = b * b + c * c;
      const float q12 = b * d + c * e;
      const float q22 = d * d + e * e + f * f;
      float* o = s_out + item * 9;
      o[0] = q00;
      o[1] = q01;
      o[2] = q02;
      o[3] = q01;
      o[4] = q11;
      o[5] = q12;
      o[6] = q02;
      o[7] = q12;
      o[8] = q22;
    }
    __syncthreads();

    // LDS -> global: 2304 float4, 9 per thread, lane stride 16 B
    float4* __restrict__ out4 = (float4*)(out + block_base * 9);
    const float4* s_out4 = (const float4*)s_out;
#pragma unroll
    for (int k = 0; k < 9; k++) {
      out4[tid + k * THREADS] = s_out4[tid + k * THREADS];
    }
  } else {
    // ---- guarded tail path (unused at 4096*1024 items) ----
    for (long long it = block_base + tid; it < n_items; it += THREADS) {
      const float a = in[it * 6 + 0];
      const float b = in[it * 6 + 1];
      const float c = in[it * 6 + 2];
      const float d = in[it * 6 + 3];
      const float e = in[it * 6 + 4];
      const float f = in[it * 6 + 5];
      float* o = out + it * 9;
      o[0] = a * a;
      o[1] = a * b;
      o[2] = a * d;
      o[3] = a * b;
      o[4] = b * b + c * c;
      o[5] = b * d + c * e;
      o[6] = a * d;
      o[7] = b * d + c * e;
      o[8] = d * d + e * e + f * f;
    }
  }
}

extern "C" void kernel_launch(void* const* d_in, const int* in_sizes, int n_in,
                              void* d_out, int out_size, void* d_ws,
                              size_t ws_size, hipStream_t stream) {
  const float* in = (const float*)d_in[0];
  float* out = (float*)d_out;
  const long long n_items = (long long)in_sizes[0] / 6;  // 4,194,304
  const long long grid =
      (n_items + ITEMS_PER_BLOCK - 1) / ITEMS_PER_BLOCK;  // 4096
  chol_to_cov_kernel<<<(int)grid, THREADS, 0, stream>>>(in, out, n_items);
}

// Round 4
// 218.118 us; speedup vs baseline: 1.1723x; 1.0253x over previous
//
#include <hip/hip_runtime.h>

// Q = L @ L^T for 3x3 lower-triangular L packed as 6 floats per item:
// packed order (row,col) = (0,0),(1,0),(1,1),(2,0),(2,1),(2,2) -> a,b,c,d,e,f
// Unique entries: u0=a*a u1=a*b u2=a*d u3=b*b+c*c u4=b*d+c*e u5=d*d+e*e+f*f
// Row-major comps [0..8] -> [u0,u1,u2, u1,u3,u4, u2,u4,u5]
//
// R2 lesson: dur_us includes harness reset (~130us fill+restore); kernel is
// already < 92us. Remaining gap: 60KB LDS -> 2 blocks/CU starved concurrency.
// This version drops s_out: each output float4 (elements 4g..4g+3) needs only
// item=4g/9's six uniques plus at most (a^2,ab,ad) of item+1 -> compute at
// store time from s_in, select via 9-way switch. LDS 24KB -> 6 blocks/CU,
// one barrier per tile, both global phases lane-contiguous float4.
// R3 fix: nontemporal builtins need native vector types, not HIP float4.

#define THREADS 256
#define IPB 1024  // items per block: s_in = 24 KB

typedef float f4 __attribute__((ext_vector_type(4)));

__global__ __launch_bounds__(THREADS) void chol_to_cov_kernel(
    const float* __restrict__ in, float* __restrict__ out, long long n_items) {
  __shared__ float s_in[IPB * 6];  // 24 KB

  const int tid = threadIdx.x;
  const long long block_base = (long long)blockIdx.x * IPB;

  if (block_base + IPB <= n_items) {
    // ---- global -> LDS: 6 float4/thread, unit lane stride ----
    const f4* __restrict__ in4 = (const f4*)(in + block_base * 6);
    f4* s4 = (f4*)s_in;
#pragma unroll
    for (int k = 0; k < 6; k++) {
      const int idx = tid + k * THREADS;
      s4[idx] = __builtin_nontemporal_load(&in4[idx]);
    }
    __syncthreads();

    // ---- compute + store: 9 float4/thread, unit lane stride ----
    f4* __restrict__ out4 = (f4*)(out + block_base * 9);
#pragma unroll
    for (int k = 0; k < 9; k++) {
      const unsigned g = (unsigned)tid + k * THREADS;  // < 2304
      const unsigned e = 4u * g;                       // first element index
      const unsigned item = e / 9u;                    // magic-mul
      const unsigned r = e - 9u * item;
      unsigned i1 = item + 1u;
      if (i1 > IPB - 1u) i1 = IPB - 1u;  // clamp (r>=6 never hits last item)

      const float* p0 = s_in + item * 6;
      const float a = p0[0], b = p0[1], c = p0[2];
      const float d = p0[3], e0 = p0[4], f = p0[5];
      const float u0 = a * a;
      const float u1 = a * b;
      const float u2 = a * d;
      const float u3 = b * b + c * c;
      const float u4 = b * d + c * e0;
      const float u5 = d * d + e0 * e0 + f * f;

      const float* p1 = s_in + i1 * 6;
      const float a1 = p1[0], b1 = p1[1], d1 = p1[3];
      const float v0 = a1 * a1;
      const float v1 = a1 * b1;
      const float v2 = a1 * d1;

      f4 o;
      switch (r) {
        case 0: o = (f4){u0, u1, u2, u1}; break;
        case 1: o = (f4){u1, u2, u1, u3}; break;
        case 2: o = (f4){u2, u1, u3, u4}; break;
        case 3: o = (f4){u1, u3, u4, u2}; break;
        case 4: o = (f4){u3, u4, u2, u4}; break;
        case 5: o = (f4){u4, u2, u4, u5}; break;
        case 6: o = (f4){u2, u4, u5, v0}; break;
        case 7: o = (f4){u4, u5, v0, v1}; break;
        default: o = (f4){u5, v0, v1, v2}; break;
      }
      __builtin_nontemporal_store(o, &out4[g]);
    }
  } else {
    // ---- guarded tail path (unused at 4096*1024 items) ----
    for (long long it = block_base + tid; it < n_items; it += THREADS) {
      const float a = in[it * 6 + 0];
      const float b = in[it * 6 + 1];
      const float c = in[it * 6 + 2];
      const float d = in[it * 6 + 3];
      const float e = in[it * 6 + 4];
      const float f = in[it * 6 + 5];
      float* o = out + it * 9;
      o[0] = a * a;
      o[1] = a * b;
      o[2] = a * d;
      o[3] = a * b;
      o[4] = b * b + c * c;
      o[5] = b * d + c * e;
      o[6] = a * d;
      o[7] = b * d + c * e;
      o[8] = d * d + e * e + f * f;
    }
  }
}

extern "C" void kernel_launch(void* const* d_in, const int* in_sizes, int n_in,
                              void* d_out, int out_size, void* d_ws,
                              size_t ws_size, hipStream_t stream) {
  const float* in = (const float*)d_in[0];
  float* out = (float*)d_out;
  const long long n_items = (long long)in_sizes[0] / 6;  // 4,194,304
  const long long grid = (n_items + IPB - 1) / IPB;      // 4096
  chol_to_cov_kernel<<<(int)grid, THREADS, 0, stream>>>(in, out, n_items);
}